// Round 6
// baseline (344.703 us; speedup 1.0000x reference)
//
#include <hip/hip_runtime.h>

#define SEQ_T 784
#define HID   128
#define S_H   160   // bf16 h-plane row stride in shorts (320B), R12-verified conflict-free
#define SB    320   // i8 h-plane row stride in bytes; reads land 2-way (free)

typedef __attribute__((ext_vector_type(8))) short  short8;
typedef __attribute__((ext_vector_type(4))) float  floatx4;
typedef __attribute__((ext_vector_type(4))) int    intx4;
typedef __attribute__((ext_vector_type(8))) float  float8;

// bf16 round-to-nearest-even on raw bits (inputs finite)
static __device__ __forceinline__ short bf16_of(float f) {
  union { float f; unsigned u; } v; v.f = f;
  return (short)((v.u + 0x7fffu + ((v.u >> 16) & 1u)) >> 16);
}

#define MFMA_BF16 __builtin_amdgcn_mfma_f32_16x16x32_bf16
#define MFMA_I8   __builtin_amdgcn_mfma_i32_16x16x64_i8

// 256 blocks x 4 batch rows (1 block/CU). R13 post-mortem: absmax 1.79 =
// saturated gates; bug was dequant m/127 (h's x127 never divided out ->
// gates 127x hot). Threshold now known: 3.008e-3; all-i8 predicted 3-6e-3 is
// a coin flip -> R14 HYBRID: n-gate (content path, slope ~1) stays bf16
// (R12-verified, 9.77e-4); r,z gates i8 (noise damped by sigmoid' <= 0.25).
// MFMA pipe/wave-step: 12 bf16 -> 4 bf16 + 4 i8 (i8 16x16x64 = 2x K/inst).
// h carry fp32 in-register; h stored BOTH bf16 (n A-frags) and i8 (r,z
// A-frags) -- writes proven non-critical (R11: write packing moved nothing).
// Dequant: d = m/(127*127) folded with LOG2E into exp2-direct sigmoids.
extern "C" __global__ void __launch_bounds__(512, 2)
gru_hyb_t(const float* __restrict__ x,    // [1024][784] fp32
          const float* __restrict__ Wi,   // [384]
          const float* __restrict__ bi,   // [384]
          const float* __restrict__ Wh,   // [384][128]
          const float* __restrict__ bh,   // [384]
          const float* __restrict__ Wfc,  // [10][128]
          const float* __restrict__ bfc,  // [10]
          float* __restrict__ out)        // [1024][10] fp32
{
  const int tid  = threadIdx.x;
  const int wv   = tid >> 6;
  const int lane = tid & 63;
  const int quad = lane >> 4;
  const int nn   = lane & 15;
  const int j    = (wv << 4) | nn;   // this lane's hidden column
  const int b0   = blockIdx.x * 4;   // 4 batch rows per block

  __shared__ __align__(16) float xs[SEQ_T][4];      // x fp32, [t][row]
  __shared__ __align__(16) short hbf[2][4 * S_H];   // h bf16 plane, dbuf
  __shared__ __align__(16) char  hq [2][4 * SB];    // h i8 plane, dbuf
  __shared__ float hfin[4][HID];

  for (int i = tid; i < 2 * 4 * S_H; i += 512) ((short*)hbf)[i] = 0;
  for (int i = tid; i < 2 * 4 * SB / 4; i += 512) ((int*)hq)[i] = 0;
  for (int i = tid; i < 4 * SEQ_T; i += 512) {
    const int r = i / SEQ_T;
    const int t = i - r * SEQ_T;
    xs[t][r] = x[(size_t)(b0 + r) * SEQ_T + t];
  }

  const float LOG2E = 1.4426950408889634f;
  const float TL2E  = 2.0f * LOG2E;

  // exp2-direct gate constants:
  // sigmoid(p) = rcp(1 + exp2(-p*log2e)); tanh(p) = 1 - 2*rcp(1 + exp2(p*2log2e))
  const float wi_rn = -Wi[j] * LOG2E;
  const float c_rn  = -(bi[j] + bh[j]) * LOG2E;
  const float wi_zn = -Wi[HID + j] * LOG2E;
  const float c_zn  = -(bi[HID + j] + bh[HID + j]) * LOG2E;
  const float win2  = Wi[2 * HID + j] * TL2E;
  const float bin2  = bi[2 * HID + j] * TL2E;
  const float bhn2  = bh[2 * HID + j] * TL2E;

  // n-gate Wh: bf16 B-frags (R12-verified map: k = kk*32 + quad*8 + e)
  short8 whn[4];
  {
    const float* wrow = Wh + (size_t)(2 * HID + j) * HID;
    #pragma unroll
    for (int kk = 0; kk < 4; ++kk) {
      float8 w = *(const float8*)(wrow + kk * 32 + quad * 8);
      short8 hi;
      #pragma unroll
      for (int e = 0; e < 8; ++e) hi[e] = bf16_of(w[e]);
      whn[kk] = hi;
    }
  }

  // r,z Wh: per-row symmetric i8, B-frag map k = kk*64 + quad*16 + e
  // (A uses the same map -> any hw k-permutation cancels in the dot product)
  intx4 wq[2][2];
  float d_rn, d_zn;   // -(m/(127*127))*log2e
  #pragma unroll
  for (int g = 0; g < 2; ++g) {
    const float* wrow = Wh + (size_t)(g * HID + j) * HID;
    float m = 0.0f;
    #pragma unroll
    for (int k8 = 0; k8 < 16; ++k8) {
      float8 w = *(const float8*)(wrow + k8 * 8);
      #pragma unroll
      for (int e = 0; e < 8; ++e) m = fmaxf(m, fabsf(w[e]));
    }
    const float inv = 127.0f / m;
    #pragma unroll
    for (int kk = 0; kk < 2; ++kk) {
      int dw[4] = {0, 0, 0, 0};
      #pragma unroll
      for (int e = 0; e < 16; ++e) {
        const int q = (int)rintf(wrow[kk * 64 + quad * 16 + e] * inv) & 0xFF;
        dw[e >> 2] |= q << (8 * (e & 3));
      }
      intx4 v = {dw[0], dw[1], dw[2], dw[3]};
      wq[g][kk] = v;
    }
    const float d = -m * (1.0f / 16129.0f) * LOG2E;   // 16129 = 127*127
    if (g == 0) d_rn = d; else d_zn = d;
  }

  float h = 0.0f;                           // h[batch=quad][j], fp32 carry
  // A[m=nn][k]: rows nn&3==0 real (batch row nn>>2 at LDS row nn>>2)
  const bool rlane  = ((nn & 3) == 0);
  const int abf_off = (nn >> 2) * S_H + quad * 8;   // shorts, + kk*32
  const int aq_off  = (nn >> 2) * SB + quad * 16;   // bytes,  + kk*64
  const int wbf_off = quad * S_H + j;               // shorts (even lanes b32)
  const int wq_off  = quad * SB + j;                // bytes (per-lane b8)
  const bool wlane  = ((nn & 1) == 0);

  __syncthreads();

  const floatx4 Zf = {0.f, 0.f, 0.f, 0.f};
  const intx4   Zi = {0, 0, 0, 0};
  short8 ah0 = {0,0,0,0,0,0,0,0}, ah1 = ah0, ah2 = ah0, ah3 = ah0;
  intx4  a0 = Zi, a1 = Zi;     // zero once; masked loads keep non-read lanes 0

  auto step = [&](const short* __restrict__ bc, const char* __restrict__ qc,
                  short* __restrict__ bn, char* __restrict__ qn, float xt) {
    if (rlane) {                 // 16 lanes/wave
      ah0 = *(const short8*)(bc + abf_off);
      ah1 = *(const short8*)(bc + abf_off + 32);
      ah2 = *(const short8*)(bc + abf_off + 64);
      ah3 = *(const short8*)(bc + abf_off + 96);
      a0  = *(const intx4*)(qc + aq_off);
      a1  = *(const intx4*)(qc + aq_off + 64);
    }
    // x-terms off the critical chain
    const float wrc = fmaf(xt, wi_rn, c_rn);
    const float wzc = fmaf(xt, wi_zn, c_zn);
    const float u   = fmaf(xt, win2, bin2);

    // r,z (i8) issue first -> drain earliest; n (bf16) chains of depth 2
    __builtin_amdgcn_s_setprio(1);
    intx4   cr = MFMA_I8(a0, wq[0][0], Zi, 0, 0, 0);
    intx4   cz = MFMA_I8(a0, wq[1][0], Zi, 0, 0, 0);
    floatx4 n0 = MFMA_BF16(ah0, whn[0], Zf, 0, 0, 0);
    floatx4 n1 = MFMA_BF16(ah1, whn[1], Zf, 0, 0, 0);
    cr = MFMA_I8(a1, wq[0][1], cr, 0, 0, 0);
    cz = MFMA_I8(a1, wq[1][1], cz, 0, 0, 0);
    n0 = MFMA_BF16(ah2, whn[2], n0, 0, 0, 0);
    n1 = MFMA_BF16(ah3, whn[3], n1, 0, 0, 0);
    __builtin_amdgcn_s_setprio(0);

    // C reg 0 = (batch row quad, column j) for both dtypes (layout
    // dtype-independent, m121-128). i32 exact; cvt exact (< 2^24).
    const float rg = __builtin_amdgcn_rcpf(
        1.0f + __builtin_amdgcn_exp2f(fmaf((float)cr[0], d_rn, wrc)));
    const float zg = __builtin_amdgcn_rcpf(
        1.0f + __builtin_amdgcn_exp2f(fmaf((float)cz[0], d_zn, wzc)));
    const float nsum = n0[0] + n1[0];
    const float t  = fmaf(rg, fmaf(TL2E, nsum, bhn2), u);
    const float ng = fmaf(-2.0f, __builtin_amdgcn_rcpf(
        1.0f + __builtin_amdgcn_exp2f(t)), 1.0f);
    h = fmaf(zg, h - ng, ng);              // z*h + (1-z)*n, fp32 carry

    // bf16 plane: DPP 0xB1 neighbor + cvt_pk (RNE), even lanes store b32
    const float hnb = __int_as_float(
        __builtin_amdgcn_mov_dpp(__float_as_int(h), 0xB1, 0xF, 0xF, true));
    int hp;
    asm("v_cvt_pk_bf16_f32 %0, %1, %2" : "=v"(hp) : "v"(h), "v"(hnb));
    if (wlane) *(int*)(bn + wbf_off) = hp;
    // i8 plane: per-lane b8 (4-way same-dword; writes not on critical path)
    qn[wq_off] = (char)(int)rintf(h * 127.0f);   // |h|<1 -> no clip
  };

  for (int t = 0; t < SEQ_T; t += 2) {
    const float xa = xs[t][quad];
    const float xb = xs[t + 1][quad];
    step(hbf[0], hq[0], hbf[1], hq[1], xa);
    __syncthreads();
    step(hbf[1], hq[1], hbf[0], hq[0], xb);
    __syncthreads();
  }

  // epilogue: logits = h @ Wfc^T + bfc (fp32), 4 rows x 10 outs
  hfin[quad][j] = h;
  __syncthreads();
  if (tid < 40) {
    const int r = tid / 10, o = tid - r * 10;
    float acc = bfc[o];
    #pragma unroll 4
    for (int k = 0; k < HID; ++k)
      acc = fmaf(hfin[r][k], Wfc[o * HID + k], acc);
    out[(size_t)(b0 + r) * 10 + o] = acc;
  }
}

extern "C" void kernel_launch(void* const* d_in, const int* in_sizes, int n_in,
                              void* d_out, int out_size, void* d_ws, size_t ws_size,
                              hipStream_t stream) {
  const float* x   = (const float*)d_in[0];
  const float* Wi  = (const float*)d_in[1];
  const float* bi  = (const float*)d_in[2];
  const float* Wh  = (const float*)d_in[3];
  const float* bh  = (const float*)d_in[4];
  const float* Wfc = (const float*)d_in[5];
  const float* bfc = (const float*)d_in[6];
  hipLaunchKernelGGL(gru_hyb_t, dim3(256), dim3(512), 0, stream,
                     x, Wi, bi, Wh, bh, Wfc, bfc, (float*)d_out);
}